// Round 16
// baseline (168.963 us; speedup 1.0000x reference)
//
#include <hip/hip_runtime.h>
#include <hip/hip_bf16.h>
#include <stdint.h>

// DeepSeek MoE: rmsnorm+router -> grouped expert FFN (2 shared + 8 routed)
// R16: ring-4 half-K-tile GEMM pipeline (m201-style): 256-wide tiles, BK
// half=32, 4 LDS slots, depth-3 prefetch, counted vmcnt(2L) (never 0
// mid-loop), ONE barrier per 32-MFMA step, stage-after-barrier (WAR safe),
// sched_barrier-pinned windows (R9 discipline). Rest = R13 (best known).

#define NTOK 2048
#define DM   1024
#define DH   1408
#define NGRP 10
#define EPSV 1.1920928955078125e-7f
#define NTILES 40
#define MAXSLOTS (NTILES * 256)

typedef __bf16 bf16x8 __attribute__((ext_vector_type(8)));
typedef float  f32x4  __attribute__((ext_vector_type(4)));
typedef unsigned short u16x8 __attribute__((ext_vector_type(8)));

__device__ __forceinline__ void async16(const void* g, void* l) {
  __builtin_amdgcn_global_load_lds(
      (const __attribute__((address_space(1))) unsigned*)g,
      (__attribute__((address_space(3))) unsigned*)l, 16, 0, 0);
}

__device__ __forceinline__ unsigned lds_off(const void* p) {
  return (unsigned)(unsigned long long)(const __attribute__((address_space(3))) char*)p;
}

__device__ __forceinline__ unsigned short f2bf(float f) {
  unsigned u = __builtin_bit_cast(unsigned, f);
  unsigned r = (u + 0x7FFFu + ((u >> 16) & 1u)) >> 16;
  return (unsigned short)r;
}
__device__ __forceinline__ float bf2f(unsigned short h) {
  unsigned u = ((unsigned)h) << 16;
  return __builtin_bit_cast(float, u);
}

__device__ __forceinline__ float4 ntload4(const float* p) {
  const f32x4* vp = (const f32x4*)p;
  f32x4 v = __builtin_nontemporal_load(vp);
  float4 r;
  r.x = v[0]; r.y = v[1]; r.z = v[2]; r.w = v[3];
  return r;
}

__device__ __forceinline__ int xcd_swizzle(int id, int nwg) {
  int q = nwg >> 3;
  return (id & 7) * q + (id >> 3);
}

// ---- transpose tile role: f32 [k0+64][n0+128] of s -> bf16 d[n][k] ----
__device__ __forceinline__ void transpose_role(
    const float* s, unsigned short* d, int C, int Kd, int k0, int n0,
    unsigned short* Lt, int tid) {
#pragma unroll
  for (int p = 0; p < 8; ++p) {
    int kr = p * 8 + (tid >> 5);
    int nc = (tid & 31) * 4;
    float4 v = ntload4(s + (size_t)(k0 + kr) * C + n0 + nc);
    int ncs = nc ^ ((kr >> 3) << 2);
    ushort4 u;
    u.x = f2bf(v.x); u.y = f2bf(v.y); u.z = f2bf(v.z); u.w = f2bf(v.w);
    *(ushort4*)(&Lt[kr * 132 + ncs]) = u;
  }
  __syncthreads();
#pragma unroll
  for (int p = 0; p < 4; ++p) {
    int chunk = p * 256 + tid;
    int n = chunk >> 3, kc = (chunk & 7) * 8;
    int nswz = n ^ ((chunk & 7) << 2);
    u16x8 uv;
#pragma unroll
    for (int j = 0; j < 8; ++j) uv[j] = Lt[(kc + j) * 132 + nswz];
    *(u16x8*)(d + (size_t)(n0 + n) * Kd + k0 + kc) = uv;
  }
}

// ---- K1: W1 transpose (1760 blocks) ∪ rmsnorm+router (2048 blocks) ----
__global__ __launch_bounds__(256) void prep_k(
    const float* __restrict__ Ws1, const float* __restrict__ W1,
    unsigned short* __restrict__ W1t,
    const float* __restrict__ x, const float* __restrict__ nw,
    const float* __restrict__ Wr, unsigned short* __restrict__ xb,
    int* __restrict__ idx2, float* __restrict__ gate2) {
  __shared__ unsigned short Lt[64 * 132];
  __shared__ float ps[4];
  __shared__ float pw[32];
  int bi = blockIdx.x;
  int tid = threadIdx.x;
  if (bi < 1760) {
    int z = bi / 176, rem = bi % 176, kb = rem / 11, nb = rem % 11;
    const float* s = (z < 2) ? Ws1 + (size_t)z * DM * DH : W1 + (size_t)(z - 2) * DM * DH;
    unsigned short* d = W1t + (size_t)z * DH * DM;
    transpose_role(s, d, DH, DM, kb * 64, nb * 128, Lt, tid);
    return;
  }
  int t = bi - 1760;
  const float4 v = *(const float4*)(x + (size_t)t * DM + tid * 4);
  float s = v.x * v.x + v.y * v.y + v.z * v.z + v.w * v.w;
#pragma unroll
  for (int o = 32; o; o >>= 1) s += __shfl_down(s, o);
  if ((tid & 63) == 0) ps[tid >> 6] = s;
  __syncthreads();
  float tot = ps[0] + ps[1] + ps[2] + ps[3];
  float r = rsqrtf(tot * (1.0f / (float)DM) + EPSV);
  const float4 wv = *(const float4*)(nw + tid * 4);
  float4 y;
  y.x = v.x * r * wv.x; y.y = v.y * r * wv.y; y.z = v.z * r * wv.z; y.w = v.w * r * wv.w;
  ushort4 u; u.x = f2bf(y.x); u.y = f2bf(y.y); u.z = f2bf(y.z); u.w = f2bf(y.w);
  *(ushort4*)(xb + (size_t)t * DM + tid * 4) = u;
  float pr[8];
#pragma unroll
  for (int e = 0; e < 8; ++e) {
    const float4 w4 = *(const float4*)(Wr + (size_t)e * DM + tid * 4);
    pr[e] = y.x * w4.x + y.y * w4.y + y.z * w4.z + y.w * w4.w;
  }
#pragma unroll
  for (int e = 0; e < 8; ++e)
#pragma unroll
    for (int o = 32; o; o >>= 1) pr[e] += __shfl_down(pr[e], o);
  if ((tid & 63) == 0) {
    int w = tid >> 6;
#pragma unroll
    for (int e = 0; e < 8; ++e) pw[w * 8 + e] = pr[e];
  }
  __syncthreads();
  if (tid == 0) {
    float af[8];
#pragma unroll
    for (int e = 0; e < 8; ++e) af[e] = pw[e] + pw[8 + e] + pw[16 + e] + pw[24 + e];
    int e1 = 0; float a1 = af[0];
#pragma unroll
    for (int e = 1; e < 8; ++e) if (af[e] > a1) { a1 = af[e]; e1 = e; }
    int e2 = -1; float a2 = -3.4e38f;
#pragma unroll
    for (int e = 0; e < 8; ++e) if (e != e1 && af[e] > a2) { a2 = af[e]; e2 = e; }
    idx2[t * 2] = e1; idx2[t * 2 + 1] = e2;
    gate2[t * 2] = a1; gate2[t * 2 + 1] = a2;
  }
}

// ---- K2: counts + tile map (256-pad) + scatter + bias tables ----
__global__ __launch_bounds__(256) void buildplace_k(
    const int* __restrict__ idx2, const float* __restrict__ gate2,
    const float* __restrict__ bs1, const float* __restrict__ b1,
    const float* __restrict__ bs2, const float* __restrict__ b2,
    int* __restrict__ tile_group, int* __restrict__ tok_list,
    float* __restrict__ gate_list, int* __restrict__ slot_of,
    float* __restrict__ b1p, float* __restrict__ b2p) {
  __shared__ int cnt_s[8], base_s[8], fill_s[8];
  int tid = threadIdx.x;
  if (tid < 8) { cnt_s[tid] = 0; fill_s[tid] = 0; }
  __syncthreads();
  for (int t = tid; t < NTOK; t += 256) {
    atomicAdd(&cnt_s[idx2[2 * t]], 1);
    atomicAdd(&cnt_s[idx2[2 * t + 1]], 1);
  }
  __syncthreads();
  if (tid == 0) {
    int tile = 16;
    for (int e = 0; e < 8; ++e) {
      base_s[e] = tile * 256;
      tile += (cnt_s[e] + 255) >> 8;
    }
    for (int i = 0; i < 16; ++i) tile_group[i] = i >> 3;
    int tt = 16;
    for (int e = 0; e < 8; ++e) {
      int nt = (cnt_s[e] + 255) >> 8;
      for (int i = 0; i < nt; ++i) tile_group[tt++] = 2 + e;
    }
    for (; tt < NTILES; ++tt) tile_group[tt] = -1;
  }
  for (int s = tid; s < MAXSLOTS; s += 256) {
    int tok; float gv;
    if (s < 2048)      { tok = s;        gv = 1.f; }
    else if (s < 4096) { tok = s - 2048; gv = 1.f; }
    else               { tok = -1;       gv = 0.f; }
    tok_list[s] = tok; gate_list[s] = gv;
  }
  for (int i = tid; i < NGRP * DH; i += 256) {
    int g = i / DH, j = i % DH;
    b1p[i] = (g < 2) ? bs1[g * DH + j] : b1[(g - 2) * DH + j];
  }
  for (int i = tid; i < NGRP * DM; i += 256) {
    int g = i >> 10, j = i & (DM - 1);
    b2p[i] = (g < 2) ? bs2[g * DM + j] : b2[(g - 2) * DM + j];
  }
  __syncthreads();
  for (int t = tid; t < NTOK; t += 256) {
#pragma unroll
    for (int k = 0; k < 2; ++k) {
      int e = idx2[t * 2 + k];
      int pos = atomicAdd(&fill_s[e], 1);
      int slot = base_s[e] + pos;
      tok_list[slot] = t;
      gate_list[slot] = gate2[t * 2 + k];
      slot_of[t * 2 + k] = slot;
    }
  }
}

#define DSR(dst, addr) asm volatile("ds_read_b128 %0, %1" : "=v"(dst) : "v"(addr))
#define VMW(n) asm volatile("s_waitcnt vmcnt(" #n ")" ::: "memory")

// ---- ring-4 half-K-tile GEMM body ----
// BM x BN tile, 512 thr (8 waves, WM x WN_), half-K = 32. LDS ring of 4
// slots (A-half BM*64B + B-half BN*64B). Depth-3 prefetch, wait vmcnt(2L).
// Swizzle sigma(row)=(row>>1)&3 on 16B chunks (<=2-way, free), src-side.
template <int KD, int ND, int BN, int WN_, int MF, int BL, bool FIRST>
__device__ __forceinline__ void gemm_body(
    int tile, int bn, char* smem,
    const unsigned short* __restrict__ A, const int* __restrict__ tok_list,
    const int* __restrict__ tile_group, const unsigned short* __restrict__ Bt,
    const float* __restrict__ biasP, const float* __restrict__ gate_list,
    unsigned short* __restrict__ Out) {
  constexpr int BM = 256, AL = 2, NF = 4;
  constexpr int L = AL + BL;                 // loads per half per thread
  constexpr int ASZ = BM * 64, BSZ = BN * 64, SLOT = ASZ + BSZ;
  constexpr int H = KD / 32;                 // number of K-halves
  int g = tile_group[tile];
  if (g < 0) return;
  int tid = threadIdx.x;
  int* rows_s = (int*)(smem + 4 * SLOT);
  float* gates_s = (float*)(smem + 4 * SLOT + 1024);
  if (tid < 256) {
    if (FIRST) {
      int tok = tok_list[tile * 256 + tid];
      rows_s[tid] = tok < 0 ? 0 : tok;
    } else {
      gates_s[tid] = gate_list[tile * 256 + tid];
    }
  }
  __syncthreads();
  // staging source pointers: dest row = p*128 + (tid>>2), chunk = tid&3
  int drow = tid >> 2, schk = tid & 3;
  const unsigned short* aS[AL];
  const unsigned short* bS[BL];
#pragma unroll
  for (int p = 0; p < AL; ++p) {
    int rl = p * 128 + drow;
    int arow = FIRST ? rows_s[rl] : tile * 256 + rl;
    aS[p] = A + (size_t)arow * KD + (schk ^ ((rl >> 1) & 3)) * 8;
  }
#pragma unroll
  for (int p = 0; p < BL; ++p) {
    int rl = p * 128 + drow;
    int brow = bn + rl; if (brow > ND - 1) brow = ND - 1;  // clamp (G1 pad)
    bS[p] = Bt + ((size_t)g * ND + brow) * KD + (schk ^ ((rl >> 1) & 3)) * 8;
  }
  int lane = tid & 63, w = tid >> 6;
  int wm = w / WN_, wn = w % WN_;
  int lr = lane & 15, hi = lane >> 4;
  int aOffB[MF], bOffB[NF];
#pragma unroll
  for (int q = 0; q < MF; ++q) {
    int row = wm * (MF * 16) + q * 16 + lr;
    aOffB[q] = row * 64 + ((hi ^ ((row >> 1) & 3)) << 4);
  }
#pragma unroll
  for (int nf = 0; nf < NF; ++nf) {
    int row = wn * 64 + nf * 16 + lr;
    bOffB[nf] = ASZ + row * 64 + ((hi ^ ((row >> 1) & 3)) << 4);
  }
  unsigned ringB[4];
#pragma unroll
  for (int s = 0; s < 4; ++s) ringB[s] = lds_off(smem + s * SLOT);
  // pinned bias preload (rule #17): keeps the counted window clean
  float bv[NF];
#pragma unroll
  for (int nf = 0; nf < NF; ++nf) {
    int col = bn + wn * 64 + nf * 16 + lr;
    int cidx = col < ND ? col : ND - 1;
    bv[nf] = biasP[g * ND + cidx];
    asm volatile("" : "+v"(bv[nf]));
  }
  f32x4 acc[MF][NF];
#pragma unroll
  for (int q = 0; q < MF; ++q)
#pragma unroll
    for (int nf = 0; nf < NF; ++nf) acc[q][nf] = (f32x4){0.f, 0.f, 0.f, 0.f};
  auto stage = [&](int h) {
    char* sb = smem + (h & 3) * SLOT;
#pragma unroll
    for (int p = 0; p < AL; ++p)
      async16(aS[p] + h * 32, sb + p * 8192 + tid * 16);
#pragma unroll
    for (int p = 0; p < BL; ++p)
      async16(bS[p] + h * 32, sb + ASZ + p * 8192 + tid * 16);
  };
  // prologue: clean vmcnt, prefetch 3 halves (pinned)
  VMW(0);
  __builtin_amdgcn_sched_barrier(0);
  stage(0); stage(1); stage(2);
  __builtin_amdgcn_sched_barrier(0);
  for (int h = 0; h < H; ++h) {
    // wait: halves h+1, h+2 may stay in flight (counted, never drain mid-loop)
    if (h < H - 2) {
      if constexpr (L == 4) VMW(8); else VMW(6);
    } else if (h == H - 2) {
      if constexpr (L == 4) VMW(4); else VMW(3);
    } else {
      VMW(0);
    }
    __builtin_amdgcn_sched_barrier(0);
    asm volatile("s_barrier" ::: "memory");  // slot h ready; readers of h-1 done
    if (h + 3 < H) {
      __builtin_amdgcn_sched_barrier(0);
      stage(h + 3);  // writes slot (h-1)&3: WAR-safe after barrier
      __builtin_amdgcn_sched_barrier(0);
    }
    f32x4 ar[MF], br[NF];
    unsigned rb = ringB[h & 3];
#pragma unroll
    for (int q = 0; q < MF; ++q) DSR(ar[q], rb + (unsigned)aOffB[q]);
#pragma unroll
    for (int nf = 0; nf < NF; ++nf) DSR(br[nf], rb + (unsigned)bOffB[nf]);
    asm volatile("s_waitcnt lgkmcnt(0)" ::: "memory");
    __builtin_amdgcn_sched_barrier(0);
    __builtin_amdgcn_s_setprio(1);
#pragma unroll
    for (int q = 0; q < MF; ++q)
#pragma unroll
      for (int nf = 0; nf < NF; ++nf)
        acc[q][nf] = __builtin_amdgcn_mfma_f32_16x16x32_bf16(
            __builtin_bit_cast(bf16x8, ar[q]), __builtin_bit_cast(bf16x8, br[nf]),
            acc[q][nf], 0, 0, 0);
    __builtin_amdgcn_s_setprio(0);
  }
#pragma unroll
  for (int nf = 0; nf < NF; ++nf) {
    int col = bn + wn * 64 + nf * 16 + lr;
    if (col < ND) {
#pragma unroll
      for (int q = 0; q < MF; ++q) {
        int rl = wm * (MF * 16) + q * 16 + hi * 4;
#pragma unroll
        for (int j = 0; j < 4; ++j) {
          float v = acc[q][nf][j] + bv[nf];
          if (FIRST) {
            v = v / (1.f + expf(-v));  // silu
            Out[(size_t)(tile * 256 + rl + j) * DH + col] = f2bf(v);
          } else {
            v *= gates_s[rl + j];
            Out[(size_t)(tile * 256 + rl + j) * DM + col] = f2bf(v);
          }
        }
      }
    }
  }
}

// ---- K3: GEMM1 256x256 (240 blocks) ∪ W2-transpose (1760 blocks) ----
__global__ __launch_bounds__(512, 2) void gemm1t_k(
    const unsigned short* __restrict__ A, const int* __restrict__ tok_list,
    const int* __restrict__ tile_group, const unsigned short* __restrict__ Bt,
    const float* __restrict__ b1p, unsigned short* __restrict__ Hb,
    const float* __restrict__ Ws2, const float* __restrict__ W2,
    unsigned short* __restrict__ W2t) {
  __shared__ char smem[4 * 32768 + 2048];  // 133 KB
  int bi = blockIdx.x;
  if (bi >= 240) {
    if (threadIdx.x >= 256) return;
    int b2 = bi - 240;
    int z = b2 / 176, rem = b2 % 176, kb = rem / 8, nb = rem % 8;
    const float* s = (z < 2) ? Ws2 + (size_t)z * DH * DM : W2 + (size_t)(z - 2) * DH * DM;
    unsigned short* d = W2t + (size_t)z * DM * DH;
    transpose_role(s, d, DM, DH, kb * 64, nb * 128, (unsigned short*)smem, threadIdx.x);
    return;
  }
  int wg = xcd_swizzle(bi, 240);
  int tile = wg / 6, bn = (wg % 6) * 256;
  // G1: BN=256, 2Mx4N waves, MF=8, BL=2
  gemm_body<DM, DH, 256, 4, 8, 2, true>(tile, bn, smem, A, tok_list, tile_group,
                                        Bt, b1p, nullptr, Hb);
}

// ---- K4: GEMM2 256x128 (320 blocks) ----
__global__ __launch_bounds__(512, 2) void gemm2_k(
    const unsigned short* __restrict__ A, const int* __restrict__ tok_list,
    const int* __restrict__ tile_group, const unsigned short* __restrict__ Bt,
    const float* __restrict__ b2p, const float* __restrict__ gate_list,
    unsigned short* __restrict__ Ob) {
  __shared__ char smem[4 * 24576 + 2048];  // 98.3 KB
  int wg = xcd_swizzle(blockIdx.x, 320);
  int tile = wg >> 3, bn = (wg & 7) * 128;
  // G2: BN=128, 4Mx2N waves, MF=4, BL=1
  gemm_body<DH, DM, 128, 2, 4, 1, false>(tile, bn, smem, A, tok_list, tile_group,
                                         Bt, b2p, gate_list, Ob);
}

// ---- K5: combine ----
__global__ __launch_bounds__(256) void combine_k(
    const float* __restrict__ x, const unsigned short* __restrict__ O,
    const int* __restrict__ slot_of, float* __restrict__ out) {
  int t = blockIdx.x, tid = threadIdx.x;
  int d = tid * 4;
  int s0 = slot_of[t * 2], s1 = slot_of[t * 2 + 1];
  float4 xv = *(const float4*)(x + (size_t)t * DM + d);
  ushort4 a = *(const ushort4*)(O + (size_t)t * DM + d);
  ushort4 b = *(const ushort4*)(O + (size_t)(2048 + t) * DM + d);
  ushort4 c = *(const ushort4*)(O + (size_t)s0 * DM + d);
  ushort4 e = *(const ushort4*)(O + (size_t)s1 * DM + d);
  float4 o;
  o.x = xv.x + bf2f(a.x) + bf2f(b.x) + bf2f(c.x) + bf2f(e.x);
  o.y = xv.y + bf2f(a.y) + bf2f(b.y) + bf2f(c.y) + bf2f(e.y);
  o.z = xv.z + bf2f(a.z) + bf2f(b.z) + bf2f(c.z) + bf2f(e.z);
  o.w = xv.w + bf2f(a.w) + bf2f(b.w) + bf2f(c.w) + bf2f(e.w);
  *(float4*)(out + (size_t)t * DM + d) = o;
}

extern "C" void kernel_launch(void* const* d_in, const int* in_sizes, int n_in,
                              void* d_out, int out_size, void* d_ws, size_t ws_size,
                              hipStream_t stream) {
  const float* x   = (const float*)d_in[0];
  const float* nw  = (const float*)d_in[1];
  const float* Wr  = (const float*)d_in[2];
  const float* Ws1 = (const float*)d_in[3];
  const float* bs1 = (const float*)d_in[4];
  const float* Ws2 = (const float*)d_in[5];
  const float* bs2 = (const float*)d_in[6];
  const float* W1  = (const float*)d_in[7];
  const float* b1  = (const float*)d_in[8];
  const float* W2  = (const float*)d_in[9];
  const float* b2  = (const float*)d_in[10];
  float* out = (float*)d_out;

  char* ws = (char*)d_ws;
  size_t off = 0;
  auto alloc = [&](size_t n) {
    size_t r = off;
    off += (n + 255) & ~(size_t)255;
    return r;
  };
  unsigned short* XnB  = (unsigned short*)(ws + alloc((size_t)NTOK * DM * 2));
  unsigned short* W1t  = (unsigned short*)(ws + alloc((size_t)NGRP * DH * DM * 2));
  unsigned short* W2t  = (unsigned short*)(ws + alloc((size_t)NGRP * DM * DH * 2));
  unsigned short* Hb   = (unsigned short*)(ws + alloc((size_t)MAXSLOTS * DH * 2));
  unsigned short* Ob   = (unsigned short*)(ws + alloc((size_t)MAXSLOTS * DM * 2));
  int*   idx2      = (int*)(ws + alloc((size_t)NTOK * 2 * 4));
  float* gate2     = (float*)(ws + alloc((size_t)NTOK * 2 * 4));
  int*   tile_group= (int*)(ws + alloc(64 * 4));
  int*   tok_list  = (int*)(ws + alloc((size_t)MAXSLOTS * 4));
  float* gate_list = (float*)(ws + alloc((size_t)MAXSLOTS * 4));
  int*   slot_of   = (int*)(ws + alloc((size_t)NTOK * 2 * 4));
  float* b1p       = (float*)(ws + alloc((size_t)NGRP * DH * 4));
  float* b2p       = (float*)(ws + alloc((size_t)NGRP * DM * 4));

  prep_k<<<1760 + NTOK, 256, 0, stream>>>(Ws1, W1, W1t, x, nw, Wr, XnB, idx2, gate2);
  buildplace_k<<<1, 256, 0, stream>>>(idx2, gate2, bs1, b1, bs2, b2,
                                      tile_group, tok_list, gate_list, slot_of, b1p, b2p);
  gemm1t_k<<<240 + 1760, 512, 0, stream>>>(
      XnB, tok_list, tile_group, W1t, b1p, Hb, Ws2, W2, W2t);
  gemm2_k<<<320, 512, 0, stream>>>(
      Hb, tok_list, tile_group, W2t, b2p, gate_list, Ob);
  combine_k<<<NTOK, 256, 0, stream>>>(x, Ob, slot_of, out);
}

// Round 18
// 141.709 us; speedup vs baseline: 1.1923x; 1.1923x over previous
//
#include <hip/hip_runtime.h>
#include <hip/hip_bf16.h>
#include <stdint.h>

// DeepSeek MoE: rmsnorm+router -> grouped expert FFN (2 shared + 8 routed)
// R18: R17 with the staging-stride bug fixed (p*4096, not p*8192 — each p
// covers 32 rows x 128B in the 128x128/BK=64 tile). Design: R13 base
// (counted-vmcnt(8) 2-barrier GEMM, 2 blocks/CU, W2-transpose folded into
// gemm1 launch) + NBN=11 unpadded W1t + 128-granular expert slot padding.

#define NTOK 2048
#define DM   1024
#define DH   1408
#define NGRP 10
#define EPSV 1.1920928955078125e-7f
#define MT_MAX 72
#define MAXSLOTS (MT_MAX * 128)

typedef __bf16 bf16x8 __attribute__((ext_vector_type(8)));
typedef float  f32x4  __attribute__((ext_vector_type(4)));
typedef unsigned short u16x8 __attribute__((ext_vector_type(8)));

__device__ __forceinline__ void async16(const void* g, void* l) {
  __builtin_amdgcn_global_load_lds(
      (const __attribute__((address_space(1))) unsigned*)g,
      (__attribute__((address_space(3))) unsigned*)l, 16, 0, 0);
}

__device__ __forceinline__ unsigned lds_off(const void* p) {
  return (unsigned)(unsigned long long)(const __attribute__((address_space(3))) char*)p;
}

__device__ __forceinline__ unsigned short f2bf(float f) {
  unsigned u = __builtin_bit_cast(unsigned, f);
  unsigned r = (u + 0x7FFFu + ((u >> 16) & 1u)) >> 16;
  return (unsigned short)r;
}
__device__ __forceinline__ float bf2f(unsigned short h) {
  unsigned u = ((unsigned)h) << 16;
  return __builtin_bit_cast(float, u);
}

__device__ __forceinline__ float4 ntload4(const float* p) {
  const f32x4* vp = (const f32x4*)p;
  f32x4 v = __builtin_nontemporal_load(vp);
  float4 r;
  r.x = v[0]; r.y = v[1]; r.z = v[2]; r.w = v[3];
  return r;
}

__device__ __forceinline__ int xcd_swizzle(int id, int nwg) {
  int q = nwg >> 3;
  return (id & 7) * q + (id >> 3);
}

// ---- transpose tile role: f32 [k0+64][n0+128] of s -> bf16 d[n][k] ----
__device__ __forceinline__ void transpose_role(
    const float* s, unsigned short* d, int C, int Kd, int k0, int n0,
    unsigned short* Lt, int tid) {
#pragma unroll
  for (int p = 0; p < 8; ++p) {
    int kr = p * 8 + (tid >> 5);
    int nc = (tid & 31) * 4;
    float4 v = ntload4(s + (size_t)(k0 + kr) * C + n0 + nc);
    int ncs = nc ^ ((kr >> 3) << 2);
    ushort4 u;
    u.x = f2bf(v.x); u.y = f2bf(v.y); u.z = f2bf(v.z); u.w = f2bf(v.w);
    *(ushort4*)(&Lt[kr * 132 + ncs]) = u;
  }
  __syncthreads();
#pragma unroll
  for (int p = 0; p < 4; ++p) {
    int chunk = p * 256 + tid;
    int n = chunk >> 3, kc = (chunk & 7) * 8;
    int nswz = n ^ ((chunk & 7) << 2);
    u16x8 uv;
#pragma unroll
    for (int j = 0; j < 8; ++j) uv[j] = Lt[(kc + j) * 132 + nswz];
    *(u16x8*)(d + (size_t)(n0 + n) * Kd + k0 + kc) = uv;
  }
}

// ---- K1: W1 transpose (1760 blocks) ∪ rmsnorm+router (2048 blocks) ----
__global__ __launch_bounds__(256) void prep_k(
    const float* __restrict__ Ws1, const float* __restrict__ W1,
    unsigned short* __restrict__ W1t,
    const float* __restrict__ x, const float* __restrict__ nw,
    const float* __restrict__ Wr, unsigned short* __restrict__ xb,
    int* __restrict__ idx2, float* __restrict__ gate2) {
  __shared__ unsigned short Lt[64 * 132];
  __shared__ float ps[4];
  __shared__ float pw[32];
  int bi = blockIdx.x;
  int tid = threadIdx.x;
  if (bi < 1760) {
    int z = bi / 176, rem = bi % 176, kb = rem / 11, nb = rem % 11;
    const float* s = (z < 2) ? Ws1 + (size_t)z * DM * DH : W1 + (size_t)(z - 2) * DM * DH;
    unsigned short* d = W1t + (size_t)z * DH * DM;
    transpose_role(s, d, DH, DM, kb * 64, nb * 128, Lt, tid);
    return;
  }
  int t = bi - 1760;
  const float4 v = *(const float4*)(x + (size_t)t * DM + tid * 4);
  float s = v.x * v.x + v.y * v.y + v.z * v.z + v.w * v.w;
#pragma unroll
  for (int o = 32; o; o >>= 1) s += __shfl_down(s, o);
  if ((tid & 63) == 0) ps[tid >> 6] = s;
  __syncthreads();
  float tot = ps[0] + ps[1] + ps[2] + ps[3];
  float r = rsqrtf(tot * (1.0f / (float)DM) + EPSV);
  const float4 wv = *(const float4*)(nw + tid * 4);
  float4 y;
  y.x = v.x * r * wv.x; y.y = v.y * r * wv.y; y.z = v.z * r * wv.z; y.w = v.w * r * wv.w;
  ushort4 u; u.x = f2bf(y.x); u.y = f2bf(y.y); u.z = f2bf(y.z); u.w = f2bf(y.w);
  *(ushort4*)(xb + (size_t)t * DM + tid * 4) = u;
  float pr[8];
#pragma unroll
  for (int e = 0; e < 8; ++e) {
    const float4 w4 = *(const float4*)(Wr + (size_t)e * DM + tid * 4);
    pr[e] = y.x * w4.x + y.y * w4.y + y.z * w4.z + y.w * w4.w;
  }
#pragma unroll
  for (int e = 0; e < 8; ++e)
#pragma unroll
    for (int o = 32; o; o >>= 1) pr[e] += __shfl_down(pr[e], o);
  if ((tid & 63) == 0) {
    int w = tid >> 6;
#pragma unroll
    for (int e = 0; e < 8; ++e) pw[w * 8 + e] = pr[e];
  }
  __syncthreads();
  if (tid == 0) {
    float af[8];
#pragma unroll
    for (int e = 0; e < 8; ++e) af[e] = pw[e] + pw[8 + e] + pw[16 + e] + pw[24 + e];
    int e1 = 0; float a1 = af[0];
#pragma unroll
    for (int e = 1; e < 8; ++e) if (af[e] > a1) { a1 = af[e]; e1 = e; }
    int e2 = -1; float a2 = -3.4e38f;
#pragma unroll
    for (int e = 0; e < 8; ++e) if (e != e1 && af[e] > a2) { a2 = af[e]; e2 = e; }
    idx2[t * 2] = e1; idx2[t * 2 + 1] = e2;
    gate2[t * 2] = a1; gate2[t * 2 + 1] = a2;
  }
}

// ---- K2: counts + 128-granular tile map + scatter + bias tables ----
__global__ __launch_bounds__(256) void buildplace_k(
    const int* __restrict__ idx2, const float* __restrict__ gate2,
    const float* __restrict__ bs1, const float* __restrict__ b1,
    const float* __restrict__ bs2, const float* __restrict__ b2,
    int* __restrict__ mt_group, int* __restrict__ tok_list,
    float* __restrict__ gate_list, int* __restrict__ slot_of,
    float* __restrict__ b1p, float* __restrict__ b2p) {
  __shared__ int cnt_s[8], base_s[8], fill_s[8];
  int tid = threadIdx.x;
  if (tid < 8) { cnt_s[tid] = 0; fill_s[tid] = 0; }
  __syncthreads();
  for (int t = tid; t < NTOK; t += 256) {
    atomicAdd(&cnt_s[idx2[2 * t]], 1);
    atomicAdd(&cnt_s[idx2[2 * t + 1]], 1);
  }
  __syncthreads();
  if (tid == 0) {
    for (int i = 0; i < 32; ++i) mt_group[i] = i >> 4;
    int mt = 32;
    for (int e = 0; e < 8; ++e) {
      base_s[e] = mt * 128;
      int nt = (cnt_s[e] + 127) >> 7;
      for (int i = 0; i < nt; ++i) mt_group[mt++] = 2 + e;
    }
    for (; mt < MT_MAX; ++mt) mt_group[mt] = -1;
  }
  for (int s = tid; s < MAXSLOTS; s += 256) {
    int tok; float gv;
    if (s < 2048)      { tok = s;        gv = 1.f; }
    else if (s < 4096) { tok = s - 2048; gv = 1.f; }
    else               { tok = -1;       gv = 0.f; }
    tok_list[s] = tok; gate_list[s] = gv;
  }
  for (int i = tid; i < NGRP * DH; i += 256) {
    int g = i / DH, j = i % DH;
    b1p[i] = (g < 2) ? bs1[g * DH + j] : b1[(g - 2) * DH + j];
  }
  for (int i = tid; i < NGRP * DM; i += 256) {
    int g = i >> 10, j = i & (DM - 1);
    b2p[i] = (g < 2) ? bs2[g * DM + j] : b2[(g - 2) * DM + j];
  }
  __syncthreads();
  for (int t = tid; t < NTOK; t += 256) {
#pragma unroll
    for (int k = 0; k < 2; ++k) {
      int e = idx2[t * 2 + k];
      int pos = atomicAdd(&fill_s[e], 1);
      int slot = base_s[e] + pos;
      tok_list[slot] = t;
      gate_list[slot] = gate2[t * 2 + k];
      slot_of[t * 2 + k] = slot;
    }
  }
}

#define DSR(dst, addr) asm volatile("ds_read_b128 %0, %1" : "=v"(dst) : "v"(addr))

// ---- grouped GEMM body: 128x128, BK=64, 4 waves, 2 blocks/CU,
//      2-buf pinned counted-vmcnt(8), asm ds_read (verified R9-R13) ----
template <int KD, int ND, bool FIRST>
__device__ __forceinline__ void gemm_body(
    int mt, int bn, char* smem,
    const unsigned short* __restrict__ A, const int* __restrict__ tok_list,
    const int* __restrict__ mt_group, const unsigned short* __restrict__ Bt,
    const float* __restrict__ biasP, const float* __restrict__ gate_list,
    unsigned short* __restrict__ Out) {
  constexpr int NK = KD / 64;
  int g = mt_group[mt];
  if (g < 0) return;
  int tid = threadIdx.x;
  unsigned short (*As)[128 * 64] = (unsigned short (*)[128 * 64])smem;
  unsigned short (*Bs)[128 * 64] = (unsigned short (*)[128 * 64])(smem + 32768);
  int* rows_s = (int*)(smem + 65536);
  float* gates_s = (float*)(smem + 66048);
  if (tid < 128) {
    if (FIRST) {
      int tok = tok_list[mt * 128 + tid];
      rows_s[tid] = tok < 0 ? 0 : tok;
    } else {
      gates_s[tid] = gate_list[mt * 128 + tid];
    }
  }
  __syncthreads();
  int drow = tid >> 3, schk = tid & 7;
  const unsigned short* aS[4];
  const unsigned short* bS[4];
#pragma unroll
  for (int p = 0; p < 4; ++p) {
    int rl = p * 32 + drow;
    int arow = FIRST ? rows_s[rl] : mt * 128 + rl;
    int sc = schk ^ (rl & 7);
    aS[p] = A + (size_t)arow * KD + sc * 8;
    bS[p] = Bt + ((size_t)g * ND + bn + rl) * KD + sc * 8;
  }
  int lane = tid & 63, w = tid >> 6;
  int wm = w >> 1, wn = w & 1;
  int lr = lane & 15, hi = lane >> 4;
  int aOff[4], bOff[4];
#pragma unroll
  for (int q = 0; q < 4; ++q) {
    int row = wm * 64 + q * 16 + lr;
    aOff[q] = row * 128 + ((hi ^ (row & 7)) << 4);
  }
#pragma unroll
  for (int nf = 0; nf < 4; ++nf) {
    int row = wn * 64 + nf * 16 + lr;
    bOff[nf] = row * 128 + ((hi ^ (row & 7)) << 4);
  }
  unsigned aBase[2] = {lds_off(&As[0][0]), lds_off(&As[1][0])};
  unsigned bBase[2] = {lds_off(&Bs[0][0]), lds_off(&Bs[1][0])};
  float bv[4];
#pragma unroll
  for (int nf = 0; nf < 4; ++nf) {
    int col = bn + wn * 64 + nf * 16 + lr;
    bv[nf] = biasP[g * ND + col];
    asm volatile("" : "+v"(bv[nf]));  // pinned preload (rule #17)
  }
  f32x4 acc[4][4];
#pragma unroll
  for (int q = 0; q < 4; ++q)
#pragma unroll
    for (int nf = 0; nf < 4; ++nf) acc[q][nf] = (f32x4){0.f, 0.f, 0.f, 0.f};
  auto stage = [&](int buf, int kt) {
#pragma unroll
    for (int p = 0; p < 4; ++p) {
      // 32 rows x 128B per p => p*4096 (R17 bug was p*8192)
      async16(aS[p] + kt * 64, (char*)&As[buf][0] + p * 4096 + tid * 16);
      async16(bS[p] + kt * 64, (char*)&Bs[buf][0] + p * 4096 + tid * 16);
    }
  };
  asm volatile("s_waitcnt vmcnt(0)" ::: "memory");
  __builtin_amdgcn_sched_barrier(0);
  stage(0, 0);
  __builtin_amdgcn_sched_barrier(0);
  int cur = 0;
  for (int kt = 0; kt < NK; ++kt) {
    if (kt + 1 < NK) {
      __builtin_amdgcn_sched_barrier(0);
      stage(cur ^ 1, kt + 1);  // exactly 8 loads enter flight here
      __builtin_amdgcn_sched_barrier(0);
      asm volatile("s_waitcnt vmcnt(8)" ::: "memory");  // tile kt landed
      __builtin_amdgcn_sched_barrier(0);
    } else {
      asm volatile("s_waitcnt vmcnt(0)" ::: "memory");
      __builtin_amdgcn_sched_barrier(0);
    }
    asm volatile("s_barrier" ::: "memory");
    f32x4 ar0[4], br0[4], ar1[4], br1[4];
#pragma unroll
    for (int q = 0; q < 4; ++q) DSR(ar0[q], aBase[cur] + (unsigned)aOff[q]);
#pragma unroll
    for (int nf = 0; nf < 4; ++nf) DSR(br0[nf], bBase[cur] + (unsigned)bOff[nf]);
#pragma unroll
    for (int q = 0; q < 4; ++q) DSR(ar1[q], aBase[cur] + (unsigned)(aOff[q] ^ 64));
#pragma unroll
    for (int nf = 0; nf < 4; ++nf) DSR(br1[nf], bBase[cur] + (unsigned)(bOff[nf] ^ 64));
    asm volatile("s_waitcnt lgkmcnt(8)" ::: "memory");  // ks0's 8 reads done
    __builtin_amdgcn_sched_barrier(0);
    __builtin_amdgcn_s_setprio(1);
#pragma unroll
    for (int q = 0; q < 4; ++q)
#pragma unroll
      for (int nf = 0; nf < 4; ++nf)
        acc[q][nf] = __builtin_amdgcn_mfma_f32_16x16x32_bf16(
            __builtin_bit_cast(bf16x8, ar0[q]), __builtin_bit_cast(bf16x8, br0[nf]),
            acc[q][nf], 0, 0, 0);
    __builtin_amdgcn_s_setprio(0);
    asm volatile("s_waitcnt lgkmcnt(0)" ::: "memory");  // ks1's reads done
    __builtin_amdgcn_sched_barrier(0);
    __builtin_amdgcn_s_setprio(1);
#pragma unroll
    for (int q = 0; q < 4; ++q)
#pragma unroll
      for (int nf = 0; nf < 4; ++nf)
        acc[q][nf] = __builtin_amdgcn_mfma_f32_16x16x32_bf16(
            __builtin_bit_cast(bf16x8, ar1[q]), __builtin_bit_cast(bf16x8, br1[nf]),
            acc[q][nf], 0, 0, 0);
    __builtin_amdgcn_s_setprio(0);
    asm volatile("s_barrier" ::: "memory");
    cur ^= 1;
  }
#pragma unroll
  for (int nf = 0; nf < 4; ++nf) {
    int col = bn + wn * 64 + nf * 16 + lr;
#pragma unroll
    for (int q = 0; q < 4; ++q) {
      int rl = wm * 64 + q * 16 + hi * 4;
#pragma unroll
      for (int j = 0; j < 4; ++j) {
        float v = acc[q][nf][j] + bv[nf];
        if (FIRST) {
          v = v / (1.f + expf(-v));  // silu
          Out[(size_t)(mt * 128 + rl + j) * DH + col] = f2bf(v);
        } else {
          v *= gates_s[rl + j];
          Out[(size_t)(mt * 128 + rl + j) * DM + col] = f2bf(v);
        }
      }
    }
  }
}

// ---- K3: GEMM1 (792 blocks, 72x11) ∪ W2-transpose (1760 blocks) ----
__global__ __launch_bounds__(256, 2) void gemm1t_k(
    const unsigned short* __restrict__ A, const int* __restrict__ tok_list,
    const int* __restrict__ mt_group, const unsigned short* __restrict__ Bt,
    const float* __restrict__ b1p, unsigned short* __restrict__ Hb,
    const float* __restrict__ Ws2, const float* __restrict__ W2,
    unsigned short* __restrict__ W2t) {
  __shared__ char smem[66560];
  int bi = blockIdx.x;
  if (bi >= MT_MAX * 11) {
    int b2 = bi - MT_MAX * 11;
    int z = b2 / 176, rem = b2 % 176, kb = rem / 8, nb = rem % 8;
    const float* s = (z < 2) ? Ws2 + (size_t)z * DH * DM : W2 + (size_t)(z - 2) * DH * DM;
    unsigned short* d = W2t + (size_t)z * DM * DH;
    transpose_role(s, d, DM, DH, kb * 64, nb * 128, (unsigned short*)smem, threadIdx.x);
    return;
  }
  int wg = xcd_swizzle(bi, MT_MAX * 11);
  int mt = wg / 11, nb = wg % 11;
  gemm_body<DM, DH, true>(mt, nb * 128, smem, A, tok_list, mt_group, Bt, b1p, nullptr, Hb);
}

// ---- K4: GEMM2 (576 blocks, 72x8) ----
__global__ __launch_bounds__(256, 2) void gemm2_k(
    const unsigned short* __restrict__ A, const int* __restrict__ tok_list,
    const int* __restrict__ mt_group, const unsigned short* __restrict__ Bt,
    const float* __restrict__ b2p, const float* __restrict__ gate_list,
    unsigned short* __restrict__ Ob) {
  __shared__ char smem[66560];
  int wg = xcd_swizzle(blockIdx.x, MT_MAX * 8);
  int mt = wg >> 3, nb = wg & 7;
  gemm_body<DH, DM, false>(mt, nb * 128, smem, A, tok_list, mt_group, Bt, b2p, gate_list, Ob);
}

// ---- K5: combine ----
__global__ __launch_bounds__(256) void combine_k(
    const float* __restrict__ x, const unsigned short* __restrict__ O,
    const int* __restrict__ slot_of, float* __restrict__ out) {
  int t = blockIdx.x, tid = threadIdx.x;
  int d = tid * 4;
  int s0 = slot_of[t * 2], s1 = slot_of[t * 2 + 1];
  float4 xv = *(const float4*)(x + (size_t)t * DM + d);
  ushort4 a = *(const ushort4*)(O + (size_t)t * DM + d);
  ushort4 b = *(const ushort4*)(O + (size_t)(2048 + t) * DM + d);
  ushort4 c = *(const ushort4*)(O + (size_t)s0 * DM + d);
  ushort4 e = *(const ushort4*)(O + (size_t)s1 * DM + d);
  float4 o;
  o.x = xv.x + bf2f(a.x) + bf2f(b.x) + bf2f(c.x) + bf2f(e.x);
  o.y = xv.y + bf2f(a.y) + bf2f(b.y) + bf2f(c.y) + bf2f(e.y);
  o.z = xv.z + bf2f(a.z) + bf2f(b.z) + bf2f(c.z) + bf2f(e.z);
  o.w = xv.w + bf2f(a.w) + bf2f(b.w) + bf2f(c.w) + bf2f(e.w);
  *(float4*)(out + (size_t)t * DM + d) = o;
}

extern "C" void kernel_launch(void* const* d_in, const int* in_sizes, int n_in,
                              void* d_out, int out_size, void* d_ws, size_t ws_size,
                              hipStream_t stream) {
  const float* x   = (const float*)d_in[0];
  const float* nw  = (const float*)d_in[1];
  const float* Wr  = (const float*)d_in[2];
  const float* Ws1 = (const float*)d_in[3];
  const float* bs1 = (const float*)d_in[4];
  const float* Ws2 = (const float*)d_in[5];
  const float* bs2 = (const float*)d_in[6];
  const float* W1  = (const float*)d_in[7];
  const float* b1  = (const float*)d_in[8];
  const float* W2  = (const float*)d_in[9];
  const float* b2  = (const float*)d_in[10];
  float* out = (float*)d_out;

  char* ws = (char*)d_ws;
  size_t off = 0;
  auto alloc = [&](size_t n) {
    size_t r = off;
    off += (n + 255) & ~(size_t)255;
    return r;
  };
  unsigned short* XnB  = (unsigned short*)(ws + alloc((size_t)NTOK * DM * 2));
  unsigned short* W1t  = (unsigned short*)(ws + alloc((size_t)NGRP * DH * DM * 2));
  unsigned short* W2t  = (unsigned short*)(ws + alloc((size_t)NGRP * DM * DH * 2));
  unsigned short* Hb   = (unsigned short*)(ws + alloc((size_t)MAXSLOTS * DH * 2));
  unsigned short* Ob   = (unsigned short*)(ws + alloc((size_t)MAXSLOTS * DM * 2));
  int*   idx2      = (int*)(ws + alloc((size_t)NTOK * 2 * 4));
  float* gate2     = (float*)(ws + alloc((size_t)NTOK * 2 * 4));
  int*   mt_group  = (int*)(ws + alloc(128 * 4));
  int*   tok_list  = (int*)(ws + alloc((size_t)MAXSLOTS * 4));
  float* gate_list = (float*)(ws + alloc((size_t)MAXSLOTS * 4));
  int*   slot_of   = (int*)(ws + alloc((size_t)NTOK * 2 * 4));
  float* b1p       = (float*)(ws + alloc((size_t)NGRP * DH * 4));
  float* b2p       = (float*)(ws + alloc((size_t)NGRP * DM * 4));

  prep_k<<<1760 + NTOK, 256, 0, stream>>>(Ws1, W1, W1t, x, nw, Wr, XnB, idx2, gate2);
  buildplace_k<<<1, 256, 0, stream>>>(idx2, gate2, bs1, b1, bs2, b2,
                                      mt_group, tok_list, gate_list, slot_of, b1p, b2p);
  gemm1t_k<<<MT_MAX * 11 + 1760, 256, 0, stream>>>(
      XnB, tok_list, mt_group, W1t, b1p, Hb, Ws2, W2, W2t);
  gemm2_k<<<MT_MAX * 8, 256, 0, stream>>>(
      Hb, tok_list, mt_group, W2t, b2p, gate_list, Ob);
  combine_k<<<NTOK, 256, 0, stream>>>(x, Ob, slot_of, out);
}